// Round 4
// baseline (490.027 us; speedup 1.0000x reference)
//
#include <hip/hip_runtime.h>
#include <hip/hip_bf16.h>

#define DIM 384
#define SEQ 3136   // 56*56
#define NBATCH 8

typedef __attribute__((ext_vector_type(8))) short short8;  // 8 x bf16 (4 VGPRs)
typedef __attribute__((ext_vector_type(4))) float fx4;
typedef __attribute__((ext_vector_type(4))) int i4;
typedef __hip_bfloat16 bf16;

#define MFMA(a,b,c) __builtin_amdgcn_mfma_f32_16x16x32_bf16(a,b,c,0,0,0)

// -------- x[b][c][n] f32 -> kb[b][n][c] bf16 (transpose + convert) --------
__global__ __launch_bounds__(256) void ktrans(const float* __restrict__ x,
                                              bf16* __restrict__ kb) {
  __shared__ float t[64][65];
  int b = blockIdx.z;
  int n0 = blockIdx.x * 64, c0 = blockIdx.y * 64;
  int tid = threadIdx.x;
  {
    int nl = tid & 63, cl = tid >> 6;
    const float* xp = x + ((size_t)b * DIM + c0) * SEQ + n0;
    #pragma unroll
    for (int p = 0; p < 16; ++p) {
      int c = cl * 16 + p;
      t[c][nl] = xp[(size_t)c * SEQ + nl];
    }
  }
  __syncthreads();
  {
    int cc = tid & 63, nr = tid >> 6;
    bf16* kp = kb + ((size_t)b * SEQ + n0) * DIM + c0;
    #pragma unroll
    for (int p = 0; p < 16; ++p) {
      int n = nr * 16 + p;
      kp[(size_t)n * DIM + cc] = __float2bfloat16(t[cc][n]);
    }
  }
}

// -------- weights f32 -> bf16 --------
__global__ __launch_bounds__(256) void kwconv(const float* __restrict__ w1,
                                              const float* __restrict__ w2,
                                              bf16* __restrict__ w1b,
                                              bf16* __restrict__ w2b) {
  int i = blockIdx.x * 256 + threadIdx.x;   // grid covers DIM*DIM exactly
  w1b[i] = __float2bfloat16(w1[i]);
  w2b[i] = __float2bfloat16(w2[i]);
}

// -------- out[r][c] = sum_k A[r][k] * Bt[c][k]   (both K-contiguous, K=384) --------
__global__ __launch_bounds__(256, 1) void kgemm(const bf16* __restrict__ A, long long Abs,
                                                const bf16* __restrict__ Bt, long long Bbs,
                                                bf16* __restrict__ out, long long Obs, int ldo) {
  __shared__ __align__(16) bf16 At[64][DIM + 8];
  __shared__ __align__(16) bf16 Bs[64][DIM + 8];
  int b = blockIdx.z;
  int tid = threadIdx.x;
  const bf16* Ab = A + (size_t)b * Abs + (size_t)blockIdx.x * 64 * DIM;
  const bf16* Bb = Bt + (size_t)b * Bbs + (size_t)blockIdx.y * 64 * DIM;
  {
    int row = tid >> 2, cb = (tid & 3) * 96;
    const i4* ga = (const i4*)(Ab + (size_t)row * DIM + cb);
    const i4* gb = (const i4*)(Bb + (size_t)row * DIM + cb);
    i4* la = (i4*)(&At[row][cb]);
    i4* lb = (i4*)(&Bs[row][cb]);
    #pragma unroll
    for (int p = 0; p < 12; ++p) { la[p] = ga[p]; lb[p] = gb[p]; }
  }
  __syncthreads();
  int wave = tid >> 6, lane = tid & 63;
  int r = lane & 15, kq = lane >> 4;
  fx4 zero = {0.f, 0.f, 0.f, 0.f};
  fx4 acc[4];
  #pragma unroll
  for (int i = 0; i < 4; ++i) acc[i] = zero;
  #pragma unroll
  for (int ks = 0; ks < 12; ++ks) {
    short8 af = *(const short8*)(&At[wave * 16 + r][ks * 32 + kq * 8]);
    #pragma unroll
    for (int ct = 0; ct < 4; ++ct) {
      short8 bfr = *(const short8*)(&Bs[ct * 16 + r][ks * 32 + kq * 8]);
      acc[ct] = MFMA(af, bfr, acc[ct]);
    }
  }
  bf16* ob = out + (size_t)b * Obs
           + (size_t)(blockIdx.x * 64 + wave * 16 + kq * 4) * ldo + blockIdx.y * 64;
  #pragma unroll
  for (int ct = 0; ct < 4; ++ct)
    #pragma unroll
    for (int rr = 0; rr < 4; ++rr)
      ob[(size_t)rr * ldo + ct * 16 + r] = __float2bfloat16(acc[ct][rr]);
}

// -------- fused attention: S = Q*K^T (no-max softmax), O = P*V / rowsum --------
// grid (8,49), 4 waves, m-tile 64, 2 barriers/iter. R3's 32x32 QK decomposition
// (halves QK LDS reads: 192->96 per block-iter; correctness-proven) with the
// register/staging fixes that R3 lacked:
//  * K staged via global_load_lds width=16: no ds_writes, no staging VGPRs.
//    Kl is LINEAR [64][384]; a 16B-chunk XOR swizzle (chunk ^= row&7) is applied
//    on the GLOBAL SOURCE address and again on the READ side (involution), so
//    QK reads are bank-optimal despite the power-of-two-free row stride.
//  * V fragments loaded per-ks2 half right before use (24 VGPR live, not 48).
//  * Pl stride 72 (16B-aligned pa reads, conflict-optimal).
// Peak ~155 VGPR + 96 acc AGPR = 251 <= 256 -> 2 waves/SIMD, no spill.
__global__ __launch_bounds__(256, 2) void kattn(const bf16* __restrict__ Qb,
                                                const bf16* __restrict__ Kb,
                                                const bf16* __restrict__ Vt,
                                                float* __restrict__ out) {
  __shared__ __align__(16) bf16 Kl[64][DIM];   // 49,152 B, swizzled 16B chunks
  __shared__ __align__(16) bf16 Pl[64][72];    //  9,216 B
  __shared__ float rsum2[2][64];               //    512 B   (total 58,880 B)

  int b = blockIdx.x;
  int n0 = blockIdx.y * 64;
  int tid = threadIdx.x;
  int wave = tid >> 6, lane = tid & 63;
  int r = lane & 15, kq = lane >> 4;
  int rh = wave >> 1;    // row-half of the 64 n-rows (32 rows)
  int chh = wave & 1;    // col-half of the 64 m-cols (32 cols)
  int s7 = r & 7;        // XOR swizzle key for this lane's K reads

  // Q fragments: this wave's 32 rows (2 x 16), full K=384 (12 k-steps). 96 VGPR.
  short8 qf[2][12];
  #pragma unroll
  for (int ri = 0; ri < 2; ++ri) {
    const bf16* qp = Qb + ((size_t)b * SEQ + n0 + rh * 32 + ri * 16 + r) * DIM + kq * 8;
    #pragma unroll
    for (int ks = 0; ks < 12; ++ks) qf[ri][ks] = *(const short8*)(qp + ks * 32);
  }
  fx4 zero = {0.f, 0.f, 0.f, 0.f};
  fx4 acc[4][6];
  #pragma unroll
  for (int i = 0; i < 4; ++i)
    #pragma unroll
    for (int j = 0; j < 6; ++j) acc[i][j] = zero;
  float rs[2][4] = {{0.f, 0.f, 0.f, 0.f}, {0.f, 0.f, 0.f, 0.f}};
  const float cexp = 0.07362223f;   // log2(e)/sqrt(384): exp(s*scale) = exp2(s*cexp)

  const bf16* kbase = Kb + (size_t)b * SEQ * DIM;
  const bf16* vbase = Vt + (size_t)b * DIM * SEQ;
  const bf16* Klf = &Kl[0][0];

  for (int im = 0; im < SEQ / 64; ++im) {
    int m0 = im * 64;
    { // stage K tile 64x384 via global_load_lds (12 x 1KB per wave).
      // dest chunk q = p*256+tid (linear); source chunk = (q%48)^(row&7) of row q/48.
      const bf16* ksrc = kbase + (size_t)m0 * DIM;
      #pragma unroll
      for (int p = 0; p < 12; ++p) {
        int q = p * 256 + tid;
        int row = q / 48;
        int cpos = q - row * 48;
        int ko = row * DIM + ((cpos ^ (row & 7)) << 3);
        __builtin_amdgcn_global_load_lds(
            (const __attribute__((address_space(1))) unsigned int*)(ksrc + ko),
            (__attribute__((address_space(3))) unsigned int*)((char*)Klf + ((p * 4 + wave) << 10)),
            16, 0, 0);
      }
    }
    __syncthreads();   // A: Kl ready (vmcnt drain); all waves done PV(im-1)
    // S = Q * K^T : this wave's 32 rows x 32 cols (2x2 of 16x16), swizzled reads
    fx4 sa[2][2] = {{zero, zero}, {zero, zero}};
    int R0r = chh * 32 + r;
    #pragma unroll
    for (int ks = 0; ks < 12; ++ks) {
      int sw = ((4 * ks + kq) ^ s7) << 3;
      short8 b0 = *(const short8*)(Klf + R0r * DIM + sw);
      short8 b1 = *(const short8*)(Klf + (R0r + 16) * DIM + sw);
      sa[0][0] = MFMA(qf[0][ks], b0, sa[0][0]);
      sa[0][1] = MFMA(qf[0][ks], b1, sa[0][1]);
      sa[1][0] = MFMA(qf[1][ks], b0, sa[1][0]);
      sa[1][1] = MFMA(qf[1][ks], b1, sa[1][1]);
    }
    // V fragments for first PV half: issue now, latency hides under exp phase
    short8 vf0[6];
    #pragma unroll
    for (int dtl = 0; dtl < 6; ++dtl) {
      int d = (wave * 6 + dtl) * 16 + r;
      vf0[dtl] = *(const short8*)(vbase + (size_t)d * SEQ + m0 + kq * 8);
    }
    // exp (no max subtraction), partial per-lane rowsum, P -> LDS
    #pragma unroll
    for (int ri = 0; ri < 2; ++ri)
      #pragma unroll
      for (int rr = 0; rr < 4; ++rr) {
        float e0 = exp2f(sa[ri][0][rr] * cexp);
        float e1 = exp2f(sa[ri][1][rr] * cexp);
        int row = rh * 32 + ri * 16 + kq * 4 + rr;
        Pl[row][chh * 32 + r]      = __float2bfloat16(e0);
        Pl[row][chh * 32 + 16 + r] = __float2bfloat16(e1);
        rs[ri][rr] += e0 + e1;
      }
    __syncthreads();   // B: Pl ready; all waves done QK -> Kl free next iter
    // PV: O[rg*16+i][d] += P[rg*16+i][m] * V[m][d], wave's 96 d-cols.
    // half 0 (m 0..31) uses vf0; half 1 loads vf1 here (covered by pa+PV0).
    {
      short8 pa[4];
      #pragma unroll
      for (int rg = 0; rg < 4; ++rg)
        pa[rg] = *(const short8*)(&Pl[rg * 16 + r][kq * 8]);
      short8 vf1[6];
      #pragma unroll
      for (int dtl = 0; dtl < 6; ++dtl) {
        int d = (wave * 6 + dtl) * 16 + r;
        vf1[dtl] = *(const short8*)(vbase + (size_t)d * SEQ + m0 + 32 + kq * 8);
      }
      #pragma unroll
      for (int dtl = 0; dtl < 6; ++dtl)
        #pragma unroll
        for (int rg = 0; rg < 4; ++rg)
          acc[rg][dtl] = MFMA(pa[rg], vf0[dtl], acc[rg][dtl]);
      #pragma unroll
      for (int rg = 0; rg < 4; ++rg)
        pa[rg] = *(const short8*)(&Pl[rg * 16 + r][32 + kq * 8]);
      #pragma unroll
      for (int dtl = 0; dtl < 6; ++dtl)
        #pragma unroll
        for (int rg = 0; rg < 4; ++rg)
          acc[rg][dtl] = MFMA(pa[rg], vf1[dtl], acc[rg][dtl]);
    }
  }
  // rowsum: reduce each wave's 32-col partial over the 16 r-lanes; the two
  // col-half waves sharing the same rows combine in the epilogue.
  #pragma unroll
  for (int ri = 0; ri < 2; ++ri)
    #pragma unroll
    for (int rr = 0; rr < 4; ++rr) {
      float v = rs[ri][rr];
      v += __shfl_xor(v, 1);
      v += __shfl_xor(v, 2);
      v += __shfl_xor(v, 4);
      v += __shfl_xor(v, 8);
      if (r == 0) rsum2[chh][rh * 32 + ri * 16 + kq * 4 + rr] = v;
    }
  __syncthreads();
  // epilogue: divide and store transposed: out[b][d][n]
  float* ob = out + (size_t)b * DIM * SEQ;
  #pragma unroll
  for (int rg = 0; rg < 4; ++rg) {
    #pragma unroll
    for (int rr = 0; rr < 4; ++rr) {
      int row = rg * 16 + kq * 4 + rr;
      float inv = 1.0f / (rsum2[0][row] + rsum2[1][row]);
      int n = n0 + row;
      #pragma unroll
      for (int dtl = 0; dtl < 6; ++dtl) {
        int d = (wave * 6 + dtl) * 16 + r;
        ob[(size_t)d * SEQ + n] = acc[rg][dtl][rr] * inv;
      }
    }
  }
}

extern "C" void kernel_launch(void* const* d_in, const int* in_sizes, int n_in,
                              void* d_out, int out_size, void* d_ws, size_t ws_size,
                              hipStream_t stream) {
  const float* x  = (const float*)d_in[0];
  const float* w1 = (const float*)d_in[1];
  const float* w2 = (const float*)d_in[2];
  float* out = (float*)d_out;

  char* ws = (char*)d_ws;
  size_t SZ = (size_t)NBATCH * SEQ * DIM * sizeof(bf16);   // 19,267,584 B
  bf16* Kb  = (bf16*)(ws);                 // [B][N][C]
  bf16* Qb  = (bf16*)(ws + SZ);            // [B][N][C]
  bf16* Vt  = (bf16*)(ws + 2 * SZ);        // [B][C][N]
  bf16* w1b = (bf16*)(ws + 3 * SZ);
  bf16* w2b = (bf16*)(ws + 3 * SZ + (size_t)DIM * DIM * sizeof(bf16));

  // 1) transpose+convert x -> Kb
  ktrans<<<dim3(SEQ / 64, DIM / 64, NBATCH), 256, 0, stream>>>(x, Kb);
  // 2) weights -> bf16
  kwconv<<<dim3(DIM * DIM / 256), 256, 0, stream>>>(w1, w2, w1b, w2b);
  // 3) Q[b][n][d] = sum_c Kb[b][n][c] * w1[d][c]
  kgemm<<<dim3(SEQ / 64, DIM / 64, NBATCH), 256, 0, stream>>>(
      Kb, (long long)SEQ * DIM, w1b, 0LL, Qb, (long long)SEQ * DIM, DIM);
  // 4) Vt[b][d][m] = sum_c w2[d][c] * Kb[b][m][c]
  kgemm<<<dim3(DIM / 64, SEQ / 64, NBATCH), 256, 0, stream>>>(
      w2b, 0LL, Kb, (long long)SEQ * DIM, Vt, (long long)DIM * SEQ, SEQ);
  // 5) fused attention -> out[b][d][n]  (batch on blockIdx.x -> one XCD per batch)
  kattn<<<dim3(NBATCH, SEQ / 64), 256, 0, stream>>>(Qb, Kb, Vt, out);
}

// Round 5
// 403.406 us; speedup vs baseline: 1.2147x; 1.2147x over previous
//
#include <hip/hip_runtime.h>
#include <hip/hip_bf16.h>

#define DIM 384
#define SEQ 3136   // 56*56
#define NBATCH 8

typedef __attribute__((ext_vector_type(8))) short short8;  // 8 x bf16 (4 VGPRs)
typedef __attribute__((ext_vector_type(4))) float fx4;
typedef __attribute__((ext_vector_type(4))) int i4;
typedef __hip_bfloat16 bf16;

#define MFMA(a,b,c) __builtin_amdgcn_mfma_f32_16x16x32_bf16(a,b,c,0,0,0)

// -------- x[b][c][n] f32 -> kb[b][n][c] bf16 (transpose + convert) --------
__global__ __launch_bounds__(256) void ktrans(const float* __restrict__ x,
                                              bf16* __restrict__ kb) {
  __shared__ float t[64][65];
  int b = blockIdx.z;
  int n0 = blockIdx.x * 64, c0 = blockIdx.y * 64;
  int tid = threadIdx.x;
  {
    int nl = tid & 63, cl = tid >> 6;
    const float* xp = x + ((size_t)b * DIM + c0) * SEQ + n0;
    #pragma unroll
    for (int p = 0; p < 16; ++p) {
      int c = cl * 16 + p;
      t[c][nl] = xp[(size_t)c * SEQ + nl];
    }
  }
  __syncthreads();
  {
    int cc = tid & 63, nr = tid >> 6;
    bf16* kp = kb + ((size_t)b * SEQ + n0) * DIM + c0;
    #pragma unroll
    for (int p = 0; p < 16; ++p) {
      int n = nr * 16 + p;
      kp[(size_t)n * DIM + cc] = __float2bfloat16(t[cc][n]);
    }
  }
}

// -------- weights f32 -> bf16 --------
__global__ __launch_bounds__(256) void kwconv(const float* __restrict__ w1,
                                              const float* __restrict__ w2,
                                              bf16* __restrict__ w1b,
                                              bf16* __restrict__ w2b) {
  int i = blockIdx.x * 256 + threadIdx.x;   // grid covers DIM*DIM exactly
  w1b[i] = __float2bfloat16(w1[i]);
  w2b[i] = __float2bfloat16(w2[i]);
}

// -------- out[r][c] = sum_k A[r][k] * Bt[c][k]   (both K-contiguous, K=384) --------
__global__ __launch_bounds__(256, 1) void kgemm(const bf16* __restrict__ A, long long Abs,
                                                const bf16* __restrict__ Bt, long long Bbs,
                                                bf16* __restrict__ out, long long Obs, int ldo) {
  __shared__ __align__(16) bf16 At[64][DIM + 8];
  __shared__ __align__(16) bf16 Bs[64][DIM + 8];
  int b = blockIdx.z;
  int tid = threadIdx.x;
  const bf16* Ab = A + (size_t)b * Abs + (size_t)blockIdx.x * 64 * DIM;
  const bf16* Bb = Bt + (size_t)b * Bbs + (size_t)blockIdx.y * 64 * DIM;
  {
    int row = tid >> 2, cb = (tid & 3) * 96;
    const i4* ga = (const i4*)(Ab + (size_t)row * DIM + cb);
    const i4* gb = (const i4*)(Bb + (size_t)row * DIM + cb);
    i4* la = (i4*)(&At[row][cb]);
    i4* lb = (i4*)(&Bs[row][cb]);
    #pragma unroll
    for (int p = 0; p < 12; ++p) { la[p] = ga[p]; lb[p] = gb[p]; }
  }
  __syncthreads();
  int wave = tid >> 6, lane = tid & 63;
  int r = lane & 15, kq = lane >> 4;
  fx4 zero = {0.f, 0.f, 0.f, 0.f};
  fx4 acc[4];
  #pragma unroll
  for (int i = 0; i < 4; ++i) acc[i] = zero;
  #pragma unroll
  for (int ks = 0; ks < 12; ++ks) {
    short8 af = *(const short8*)(&At[wave * 16 + r][ks * 32 + kq * 8]);
    #pragma unroll
    for (int ct = 0; ct < 4; ++ct) {
      short8 bfr = *(const short8*)(&Bs[ct * 16 + r][ks * 32 + kq * 8]);
      acc[ct] = MFMA(af, bfr, acc[ct]);
    }
  }
  bf16* ob = out + (size_t)b * Obs
           + (size_t)(blockIdx.x * 64 + wave * 16 + kq * 4) * ldo + blockIdx.y * 64;
  #pragma unroll
  for (int ct = 0; ct < 4; ++ct)
    #pragma unroll
    for (int rr = 0; rr < 4; ++rr)
      ob[(size_t)rr * ldo + ct * 16 + r] = __float2bfloat16(acc[ct][rr]);
}

// -------- fused attention: S = Q*K^T (no-max softmax), O = P*V / rowsum --------
// grid (8,49), 4 waves, m-tile 64, 2 barriers/iter. R4's proven pieces kept:
//  * K staged via global_load_lds width=16 (zero staging VGPRs), linear Kl with
//    16B-chunk XOR swizzle (chunk ^= row&7) on BOTH global source and read side
//    (involution) -> bank-minimal QK reads despite linear row stride.
//  * 32x32 QK per wave (2 A x 2 B frags): halves QK LDS reads (192->96/blk-iter).
// NEW vs R4 (the spill fix): no V preloads held across phases. PV uses a rolling
// 2-fragment V prefetch (8 VGPR live) with the first fragment issued just before
// barrier B. Per-phase arch-VGPR live sets: staging ~104, QK ~124, exp ~120,
// PV ~126 -- all <= the 128 cap that acc's ~128 AGPRs impose at 2 waves/SIMD.
__global__ __launch_bounds__(256, 2) void kattn(const bf16* __restrict__ Qb,
                                                const bf16* __restrict__ Kb,
                                                const bf16* __restrict__ Vt,
                                                float* __restrict__ out) {
  __shared__ __align__(16) bf16 Kl[64][DIM];   // 49,152 B, swizzled 16B chunks
  __shared__ __align__(16) bf16 Pl[64][72];    //  9,216 B
  __shared__ float rsum2[2][64];               //    512 B   (total 58,880 B)

  int b = blockIdx.x;
  int n0 = blockIdx.y * 64;
  int tid = threadIdx.x;
  int wave = tid >> 6, lane = tid & 63;
  int r = lane & 15, kq = lane >> 4;
  int rh = wave >> 1;    // row-half of the 64 n-rows (32 rows)
  int chh = wave & 1;    // col-half of the 64 m-cols (32 cols)
  int s7 = r & 7;        // XOR swizzle key for this lane's K reads

  // Q fragments: this wave's 32 rows (2 x 16), full K=384 (12 k-steps). 96 VGPR.
  short8 qf[2][12];
  #pragma unroll
  for (int ri = 0; ri < 2; ++ri) {
    const bf16* qp = Qb + ((size_t)b * SEQ + n0 + rh * 32 + ri * 16 + r) * DIM + kq * 8;
    #pragma unroll
    for (int ks = 0; ks < 12; ++ks) qf[ri][ks] = *(const short8*)(qp + ks * 32);
  }
  fx4 zero = {0.f, 0.f, 0.f, 0.f};
  fx4 acc[4][6];
  #pragma unroll
  for (int i = 0; i < 4; ++i)
    #pragma unroll
    for (int j = 0; j < 6; ++j) acc[i][j] = zero;
  float rs[2][4] = {{0.f, 0.f, 0.f, 0.f}, {0.f, 0.f, 0.f, 0.f}};
  const float cexp = 0.07362223f;   // log2(e)/sqrt(384): exp(s*scale) = exp2(s*cexp)

  const bf16* kbase = Kb + (size_t)b * SEQ * DIM;
  const bf16* vbase = Vt + (size_t)b * DIM * SEQ;
  const bf16* Klf = &Kl[0][0];

  for (int im = 0; im < SEQ / 64; ++im) {
    int m0 = im * 64;
    { // stage K tile 64x384 via global_load_lds (12 x 1KB per wave).
      // dest chunk q = p*256+tid (linear); source chunk = (q%48)^(row&7) of row q/48.
      const bf16* ksrc = kbase + (size_t)m0 * DIM;
      #pragma unroll
      for (int p = 0; p < 12; ++p) {
        int q = p * 256 + tid;
        int row = q / 48;
        int cpos = q - row * 48;
        int ko = row * DIM + ((cpos ^ (row & 7)) << 3);
        __builtin_amdgcn_global_load_lds(
            (const __attribute__((address_space(1))) unsigned int*)(ksrc + ko),
            (__attribute__((address_space(3))) unsigned int*)((char*)Klf + ((p * 4 + wave) << 10)),
            16, 0, 0);
      }
    }
    __syncthreads();   // A: Kl ready (vmcnt drain); all waves done PV(im-1)
    // S = Q * K^T : this wave's 32 rows x 32 cols (2x2 of 16x16), swizzled reads
    fx4 sa[2][2] = {{zero, zero}, {zero, zero}};
    int R0r = chh * 32 + r;
    #pragma unroll
    for (int ks = 0; ks < 12; ++ks) {
      int sw = ((4 * ks + kq) ^ s7) << 3;
      short8 b0 = *(const short8*)(Klf + R0r * DIM + sw);
      short8 b1 = *(const short8*)(Klf + (R0r + 16) * DIM + sw);
      sa[0][0] = MFMA(qf[0][ks], b0, sa[0][0]);
      sa[0][1] = MFMA(qf[0][ks], b1, sa[0][1]);
      sa[1][0] = MFMA(qf[1][ks], b0, sa[1][0]);
      sa[1][1] = MFMA(qf[1][ks], b1, sa[1][1]);
    }
    // exp (no max subtraction), partial per-lane rowsum, P -> LDS
    #pragma unroll
    for (int ri = 0; ri < 2; ++ri)
      #pragma unroll
      for (int rr = 0; rr < 4; ++rr) {
        float e0 = exp2f(sa[ri][0][rr] * cexp);
        float e1 = exp2f(sa[ri][1][rr] * cexp);
        int row = rh * 32 + ri * 16 + kq * 4 + rr;
        Pl[row][chh * 32 + r]      = __float2bfloat16(e0);
        Pl[row][chh * 32 + 16 + r] = __float2bfloat16(e1);
        rs[ri][rr] += e0 + e1;
      }
    // pre-issue first V fragment: latency hides under barrier + pa reads
    short8 vcur = *(const short8*)(vbase + (size_t)(wave * 96 + r) * SEQ + m0 + kq * 8);
    __syncthreads();   // B: Pl ready; all waves done QK -> Kl free next iter
    // PV: O[rg*16+i][d] += P[rg*16+i][m] * V[m][d], wave's 96 d-cols.
    // Rolling 2-fragment V prefetch: load frag t+1 while MFMAing frag t.
    #pragma unroll
    for (int ks2 = 0; ks2 < 2; ++ks2) {
      short8 pa[4];
      #pragma unroll
      for (int rg = 0; rg < 4; ++rg)
        pa[rg] = *(const short8*)(&Pl[rg * 16 + r][ks2 * 32 + kq * 8]);
      #pragma unroll
      for (int dtl = 0; dtl < 6; ++dtl) {
        short8 vnext = vcur;
        if (!(ks2 == 1 && dtl == 5)) {
          int t1 = ks2 * 6 + dtl + 1;
          int k1 = t1 / 6, d1 = t1 - (k1 * 6);
          vnext = *(const short8*)(vbase + (size_t)((wave * 6 + d1) * 16 + r) * SEQ
                                   + m0 + k1 * 32 + kq * 8);
        }
        #pragma unroll
        for (int rg = 0; rg < 4; ++rg)
          acc[rg][dtl] = MFMA(pa[rg], vcur, acc[rg][dtl]);
        vcur = vnext;
      }
    }
  }
  // rowsum: reduce each wave's 32-col partial over the 16 r-lanes; the two
  // col-half waves sharing the same rows combine in the epilogue.
  #pragma unroll
  for (int ri = 0; ri < 2; ++ri)
    #pragma unroll
    for (int rr = 0; rr < 4; ++rr) {
      float v = rs[ri][rr];
      v += __shfl_xor(v, 1);
      v += __shfl_xor(v, 2);
      v += __shfl_xor(v, 4);
      v += __shfl_xor(v, 8);
      if (r == 0) rsum2[chh][rh * 32 + ri * 16 + kq * 4 + rr] = v;
    }
  __syncthreads();
  // epilogue: divide and store transposed: out[b][d][n]
  float* ob = out + (size_t)b * DIM * SEQ;
  #pragma unroll
  for (int rg = 0; rg < 4; ++rg) {
    #pragma unroll
    for (int rr = 0; rr < 4; ++rr) {
      int row = rg * 16 + kq * 4 + rr;
      float inv = 1.0f / (rsum2[0][row] + rsum2[1][row]);
      int n = n0 + row;
      #pragma unroll
      for (int dtl = 0; dtl < 6; ++dtl) {
        int d = (wave * 6 + dtl) * 16 + r;
        ob[(size_t)d * SEQ + n] = acc[rg][dtl][rr] * inv;
      }
    }
  }
}

extern "C" void kernel_launch(void* const* d_in, const int* in_sizes, int n_in,
                              void* d_out, int out_size, void* d_ws, size_t ws_size,
                              hipStream_t stream) {
  const float* x  = (const float*)d_in[0];
  const float* w1 = (const float*)d_in[1];
  const float* w2 = (const float*)d_in[2];
  float* out = (float*)d_out;

  char* ws = (char*)d_ws;
  size_t SZ = (size_t)NBATCH * SEQ * DIM * sizeof(bf16);   // 19,267,584 B
  bf16* Kb  = (bf16*)(ws);                 // [B][N][C]
  bf16* Qb  = (bf16*)(ws + SZ);            // [B][N][C]
  bf16* Vt  = (bf16*)(ws + 2 * SZ);        // [B][C][N]
  bf16* w1b = (bf16*)(ws + 3 * SZ);
  bf16* w2b = (bf16*)(ws + 3 * SZ + (size_t)DIM * DIM * sizeof(bf16));

  // 1) transpose+convert x -> Kb
  ktrans<<<dim3(SEQ / 64, DIM / 64, NBATCH), 256, 0, stream>>>(x, Kb);
  // 2) weights -> bf16
  kwconv<<<dim3(DIM * DIM / 256), 256, 0, stream>>>(w1, w2, w1b, w2b);
  // 3) Q[b][n][d] = sum_c Kb[b][n][c] * w1[d][c]
  kgemm<<<dim3(SEQ / 64, DIM / 64, NBATCH), 256, 0, stream>>>(
      Kb, (long long)SEQ * DIM, w1b, 0LL, Qb, (long long)SEQ * DIM, DIM);
  // 4) Vt[b][d][m] = sum_c w2[d][c] * Kb[b][m][c]
  kgemm<<<dim3(DIM / 64, SEQ / 64, NBATCH), 256, 0, stream>>>(
      w2b, 0LL, Kb, (long long)SEQ * DIM, Vt, (long long)DIM * SEQ, SEQ);
  // 5) fused attention -> out[b][d][n]  (batch on blockIdx.x -> one XCD per batch)
  kattn<<<dim3(NBATCH, SEQ / 64), 256, 0, stream>>>(Qb, Kb, Vt, out);
}

// Round 6
// 385.187 us; speedup vs baseline: 1.2722x; 1.0473x over previous
//
#include <hip/hip_runtime.h>
#include <hip/hip_bf16.h>

#define DIM 384
#define SEQ 3136   // 56*56
#define NBATCH 8

typedef __attribute__((ext_vector_type(8))) short short8;  // 8 x bf16 (4 VGPRs)
typedef __attribute__((ext_vector_type(4))) float fx4;
typedef __attribute__((ext_vector_type(4))) int i4;
typedef __hip_bfloat16 bf16;

#define MFMA(a,b,c) __builtin_amdgcn_mfma_f32_16x16x32_bf16(a,b,c,0,0,0)

// -------- x[b][c][n] f32 -> kb[b][n][c] bf16 (transpose + convert) --------
__global__ __launch_bounds__(256) void ktrans(const float* __restrict__ x,
                                              bf16* __restrict__ kb) {
  __shared__ float t[64][65];
  int b = blockIdx.z;
  int n0 = blockIdx.x * 64, c0 = blockIdx.y * 64;
  int tid = threadIdx.x;
  {
    int nl = tid & 63, cl = tid >> 6;
    const float* xp = x + ((size_t)b * DIM + c0) * SEQ + n0;
    #pragma unroll
    for (int p = 0; p < 16; ++p) {
      int c = cl * 16 + p;
      t[c][nl] = xp[(size_t)c * SEQ + nl];
    }
  }
  __syncthreads();
  {
    int cc = tid & 63, nr = tid >> 6;
    bf16* kp = kb + ((size_t)b * SEQ + n0) * DIM + c0;
    #pragma unroll
    for (int p = 0; p < 16; ++p) {
      int n = nr * 16 + p;
      kp[(size_t)n * DIM + cc] = __float2bfloat16(t[cc][n]);
    }
  }
}

// -------- weights f32 -> bf16 --------
__global__ __launch_bounds__(256) void kwconv(const float* __restrict__ w1,
                                              const float* __restrict__ w2,
                                              bf16* __restrict__ w1b,
                                              bf16* __restrict__ w2b) {
  int i = blockIdx.x * 256 + threadIdx.x;   // grid covers DIM*DIM exactly
  w1b[i] = __float2bfloat16(w1[i]);
  w2b[i] = __float2bfloat16(w2[i]);
}

// -------- out[r][c] = sum_k A[r][k] * Bt[c][k]   (both K-contiguous, K=384) --------
__global__ __launch_bounds__(256, 1) void kgemm(const bf16* __restrict__ A, long long Abs,
                                                const bf16* __restrict__ Bt, long long Bbs,
                                                bf16* __restrict__ out, long long Obs, int ldo) {
  __shared__ __align__(16) bf16 At[64][DIM + 8];
  __shared__ __align__(16) bf16 Bs[64][DIM + 8];
  int b = blockIdx.z;
  int tid = threadIdx.x;
  const bf16* Ab = A + (size_t)b * Abs + (size_t)blockIdx.x * 64 * DIM;
  const bf16* Bb = Bt + (size_t)b * Bbs + (size_t)blockIdx.y * 64 * DIM;
  {
    int row = tid >> 2, cb = (tid & 3) * 96;
    const i4* ga = (const i4*)(Ab + (size_t)row * DIM + cb);
    const i4* gb = (const i4*)(Bb + (size_t)row * DIM + cb);
    i4* la = (i4*)(&At[row][cb]);
    i4* lb = (i4*)(&Bs[row][cb]);
    #pragma unroll
    for (int p = 0; p < 12; ++p) { la[p] = ga[p]; lb[p] = gb[p]; }
  }
  __syncthreads();
  int wave = tid >> 6, lane = tid & 63;
  int r = lane & 15, kq = lane >> 4;
  fx4 zero = {0.f, 0.f, 0.f, 0.f};
  fx4 acc[4];
  #pragma unroll
  for (int i = 0; i < 4; ++i) acc[i] = zero;
  #pragma unroll
  for (int ks = 0; ks < 12; ++ks) {
    short8 af = *(const short8*)(&At[wave * 16 + r][ks * 32 + kq * 8]);
    #pragma unroll
    for (int ct = 0; ct < 4; ++ct) {
      short8 bfr = *(const short8*)(&Bs[ct * 16 + r][ks * 32 + kq * 8]);
      acc[ct] = MFMA(af, bfr, acc[ct]);
    }
  }
  bf16* ob = out + (size_t)b * Obs
           + (size_t)(blockIdx.x * 64 + wave * 16 + kq * 4) * ldo + blockIdx.y * 64;
  #pragma unroll
  for (int ct = 0; ct < 4; ++ct)
    #pragma unroll
    for (int rr = 0; rr < 4; ++rr)
      ob[(size_t)rr * ldo + ct * 16 + r] = __float2bfloat16(acc[ct][rr]);
}

// -------- fused attention: S = Q*K^T (no-max softmax), O = P*V / rowsum --------
// R0's exact decomposition (grid (8,49), 4 waves, m-tile 64, 16x64 QK per wave,
// d-split PV, Pl exchange, 2 barriers/iter) with re-phased memory issue:
//  * K staged by global_load_lds width=16 into LINEAR Kl[64][384] with 16B-chunk
//    XOR involution (chunk ^= row&7) on global source + read side (R4-proven).
//    No ds_writes, no staging registers.
//  * DMA for tile t+1 issued right AFTER barrier B -> flight covered by PV(t);
//    the vmcnt(0) drain at barrier A is then free.
//  * V(t) gathers issued right AFTER barrier A -> latency covered by QK+exp;
//    complete by the drain at barrier B. Single V buffer; liveness == R0.
// Per-phase arch VGPRs match R0 (qf 48 + vf 48 + sa 16 + misc ~= 128).
__global__ __launch_bounds__(256, 2) void kattn(const bf16* __restrict__ Qb,
                                                const bf16* __restrict__ Kb,
                                                const bf16* __restrict__ Vt,
                                                float* __restrict__ out) {
  __shared__ __align__(16) bf16 Kl[64][DIM];       // 49,152 B, linear, XOR chunks
  __shared__ __align__(16) bf16 Pl[4][16][68];     //  8,704 B
  __shared__ float rsum[64];                       //    256 B  (total 58,112 B)

  int b = blockIdx.x;
  int n0 = blockIdx.y * 64;
  int tid = threadIdx.x;
  int wave = tid >> 6, lane = tid & 63;
  int r = lane & 15, kq = lane >> 4;
  int s7 = r & 7;

  // Q fragments for this wave's 16 rows, full K=384 (12 k-steps)
  short8 qf[12];
  {
    const bf16* qp = Qb + ((size_t)b * SEQ + n0 + wave * 16 + r) * DIM + kq * 8;
    #pragma unroll
    for (int ks = 0; ks < 12; ++ks) qf[ks] = *(const short8*)(qp + ks * 32);
  }
  fx4 zero = {0.f, 0.f, 0.f, 0.f};
  fx4 acc[4][6];
  #pragma unroll
  for (int i = 0; i < 4; ++i)
    #pragma unroll
    for (int j = 0; j < 6; ++j) acc[i][j] = zero;
  float rs[4] = {0.f, 0.f, 0.f, 0.f};
  const float cexp = 0.07362223f;   // log2(e)/sqrt(384): exp(s*scale) = exp2(s*cexp)

  const bf16* kbase = Kb + (size_t)b * SEQ * DIM;
  const bf16* vbase = Vt + (size_t)b * DIM * SEQ;
  const bf16* Klf = &Kl[0][0];

  // stage K tile m0 via global_load_lds: 12 x 1KB per wave. LDS dest linear;
  // global source chunk = (cpos ^ (row&7)) of row (involution with read side).
#define STAGE_K(m0_)                                                            \
  {                                                                             \
    const bf16* ksrc = kbase + (size_t)(m0_) * DIM;                             \
    _Pragma("unroll")                                                           \
    for (int p = 0; p < 12; ++p) {                                              \
      int q = p * 256 + tid;                                                    \
      int row = q / 48;                                                         \
      int cpos = q - row * 48;                                                  \
      int ko = row * DIM + ((cpos ^ (row & 7)) << 3);                           \
      __builtin_amdgcn_global_load_lds(                                         \
          (const __attribute__((address_space(1))) unsigned int*)(ksrc + ko),   \
          (__attribute__((address_space(3))) unsigned int*)((char*)Klf + ((p * 4 + wave) << 10)), \
          16, 0, 0);                                                            \
    }                                                                           \
  }

  STAGE_K(0);
  __syncthreads();   // A(0): Kl ready

  for (int im = 0; im < SEQ / 64; ++im) {
    int m0 = im * 64;
    // V fragments for THIS tile: issued post-A, latency covered by QK + exp
    short8 vf[2][6];
    #pragma unroll
    for (int ks2 = 0; ks2 < 2; ++ks2)
      #pragma unroll
      for (int dtl = 0; dtl < 6; ++dtl) {
        int d = (wave * 6 + dtl) * 16 + r;
        vf[ks2][dtl] = *(const short8*)(vbase + (size_t)d * SEQ + m0 + ks2 * 32 + kq * 8);
      }
    // S = Q * K^T : wave's 16 rows x 64 cols (swizzled Kl reads)
    fx4 sa[4];
    #pragma unroll
    for (int ct = 0; ct < 4; ++ct) sa[ct] = zero;
    #pragma unroll
    for (int ks = 0; ks < 12; ++ks) {
      int sw = ((4 * ks + kq) ^ s7) << 3;
      #pragma unroll
      for (int ct = 0; ct < 4; ++ct) {
        short8 bfr = *(const short8*)(Klf + (ct * 16 + r) * DIM + sw);
        sa[ct] = MFMA(qf[ks], bfr, sa[ct]);
      }
    }
    // exp (no max subtraction), partial rowsum, P -> LDS
    #pragma unroll
    for (int rr = 0; rr < 4; ++rr) {
      float e0 = exp2f(sa[0][rr] * cexp);
      float e1 = exp2f(sa[1][rr] * cexp);
      float e2 = exp2f(sa[2][rr] * cexp);
      float e3 = exp2f(sa[3][rr] * cexp);
      int row = kq * 4 + rr;
      Pl[wave][row][r]      = __float2bfloat16(e0);
      Pl[wave][row][16 + r] = __float2bfloat16(e1);
      Pl[wave][row][32 + r] = __float2bfloat16(e2);
      Pl[wave][row][48 + r] = __float2bfloat16(e3);
      rs[rr] += (e0 + e1) + (e2 + e3);
    }
    __syncthreads();   // B: Pl ready; all waves done QK -> Kl free
    // issue DMA for next K tile: flight covered by PV below
    if (im + 1 < SEQ / 64) STAGE_K(m0 + 64);
    // PV: O[rg*16+i][d] += P[rg*16+i][m] * V[m][d], wave's 96 d-cols
    #pragma unroll
    for (int ks2 = 0; ks2 < 2; ++ks2) {
      short8 pa[4];
      #pragma unroll
      for (int rg = 0; rg < 4; ++rg)
        pa[rg] = *(const short8*)(&Pl[rg][r][ks2 * 32 + kq * 8]);
      #pragma unroll
      for (int dtl = 0; dtl < 6; ++dtl) {
        #pragma unroll
        for (int rg = 0; rg < 4; ++rg)
          acc[rg][dtl] = MFMA(pa[rg], vf[ks2][dtl], acc[rg][dtl]);
      }
    }
    __syncthreads();   // A(t+1): DMA drained (covered by PV); Pl free next iter
  }
  // final rowsum reduce over the 16 r-lanes (cols partition), share across waves
  #pragma unroll
  for (int rr = 0; rr < 4; ++rr) {
    float v = rs[rr];
    v += __shfl_xor(v, 1);
    v += __shfl_xor(v, 2);
    v += __shfl_xor(v, 4);
    v += __shfl_xor(v, 8);
    if (r == 0) rsum[wave * 16 + kq * 4 + rr] = v;
  }
  __syncthreads();
  // epilogue: divide and store transposed: out[b][d][n]
  float* ob = out + (size_t)b * DIM * SEQ;
  #pragma unroll
  for (int rg = 0; rg < 4; ++rg) {
    #pragma unroll
    for (int rr = 0; rr < 4; ++rr) {
      float inv = 1.0f / rsum[rg * 16 + kq * 4 + rr];
      int n = n0 + rg * 16 + kq * 4 + rr;
      #pragma unroll
      for (int dtl = 0; dtl < 6; ++dtl) {
        int d = (wave * 6 + dtl) * 16 + r;
        ob[(size_t)d * SEQ + n] = acc[rg][dtl][rr] * inv;
      }
    }
  }
#undef STAGE_K
}

extern "C" void kernel_launch(void* const* d_in, const int* in_sizes, int n_in,
                              void* d_out, int out_size, void* d_ws, size_t ws_size,
                              hipStream_t stream) {
  const float* x  = (const float*)d_in[0];
  const float* w1 = (const float*)d_in[1];
  const float* w2 = (const float*)d_in[2];
  float* out = (float*)d_out;

  char* ws = (char*)d_ws;
  size_t SZ = (size_t)NBATCH * SEQ * DIM * sizeof(bf16);   // 19,267,584 B
  bf16* Kb  = (bf16*)(ws);                 // [B][N][C]
  bf16* Qb  = (bf16*)(ws + SZ);            // [B][N][C]
  bf16* Vt  = (bf16*)(ws + 2 * SZ);        // [B][C][N]
  bf16* w1b = (bf16*)(ws + 3 * SZ);
  bf16* w2b = (bf16*)(ws + 3 * SZ + (size_t)DIM * DIM * sizeof(bf16));

  // 1) transpose+convert x -> Kb
  ktrans<<<dim3(SEQ / 64, DIM / 64, NBATCH), 256, 0, stream>>>(x, Kb);
  // 2) weights -> bf16
  kwconv<<<dim3(DIM * DIM / 256), 256, 0, stream>>>(w1, w2, w1b, w2b);
  // 3) Q[b][n][d] = sum_c Kb[b][n][c] * w1[d][c]
  kgemm<<<dim3(SEQ / 64, DIM / 64, NBATCH), 256, 0, stream>>>(
      Kb, (long long)SEQ * DIM, w1b, 0LL, Qb, (long long)SEQ * DIM, DIM);
  // 4) Vt[b][d][m] = sum_c w2[d][c] * Kb[b][m][c]
  kgemm<<<dim3(DIM / 64, SEQ / 64, NBATCH), 256, 0, stream>>>(
      w2b, 0LL, Kb, (long long)SEQ * DIM, Vt, (long long)DIM * SEQ, SEQ);
  // 5) fused attention -> out[b][d][n]  (batch on blockIdx.x -> one XCD per batch)
  kattn<<<dim3(NBATCH, SEQ / 64), 256, 0, stream>>>(Qb, Kb, Vt, out);
}

// Round 7
// 279.356 us; speedup vs baseline: 1.7541x; 1.3788x over previous
//
#include <hip/hip_runtime.h>
#include <hip/hip_bf16.h>

#define DIM 384
#define SEQ 3136   // 56*56
#define NBATCH 8

typedef __attribute__((ext_vector_type(8))) short short8;  // 8 x bf16 (4 VGPRs)
typedef __attribute__((ext_vector_type(4))) float fx4;
typedef __attribute__((ext_vector_type(4))) int i4;
typedef __hip_bfloat16 bf16;

#define MFMA(a,b,c) __builtin_amdgcn_mfma_f32_16x16x32_bf16(a,b,c,0,0,0)

// -------- x[b][c][n] f32 -> kb[b][n][c] bf16 (transpose + convert) --------
__global__ __launch_bounds__(256) void ktrans(const float* __restrict__ x,
                                              bf16* __restrict__ kb) {
  __shared__ float t[64][65];
  int b = blockIdx.z;
  int n0 = blockIdx.x * 64, c0 = blockIdx.y * 64;
  int tid = threadIdx.x;
  {
    int nl = tid & 63, cl = tid >> 6;
    const float* xp = x + ((size_t)b * DIM + c0) * SEQ + n0;
    #pragma unroll
    for (int p = 0; p < 16; ++p) {
      int c = cl * 16 + p;
      t[c][nl] = xp[(size_t)c * SEQ + nl];
    }
  }
  __syncthreads();
  {
    int cc = tid & 63, nr = tid >> 6;
    bf16* kp = kb + ((size_t)b * SEQ + n0) * DIM + c0;
    #pragma unroll
    for (int p = 0; p < 16; ++p) {
      int n = nr * 16 + p;
      kp[(size_t)n * DIM + cc] = __float2bfloat16(t[cc][n]);
    }
  }
}

// -------- weights f32 -> bf16 --------
__global__ __launch_bounds__(256) void kwconv(const float* __restrict__ w1,
                                              const float* __restrict__ w2,
                                              bf16* __restrict__ w1b,
                                              bf16* __restrict__ w2b) {
  int i = blockIdx.x * 256 + threadIdx.x;   // grid covers DIM*DIM exactly
  w1b[i] = __float2bfloat16(w1[i]);
  w2b[i] = __float2bfloat16(w2[i]);
}

// -------- out[r][c] = sum_k A[r][k] * Bt[c][k]   (both K-contiguous, K=384) --------
// K split into two 192-wide staged steps: LDS 2 x 64 x 200 x 2B = 51,200 B
// -> 3 blocks/CU (was 100,352 B -> 1 block/CU). Accumulator carried across
// steps; fragment indexing / bank profile identical to the proven full-K
// version (row stride 400 B == 784 B mod-32-bank pattern). One extra barrier
// pair per block; MFMA count unchanged.
__global__ __launch_bounds__(256, 3) void kgemm(const bf16* __restrict__ A, long long Abs,
                                                const bf16* __restrict__ Bt, long long Bbs,
                                                bf16* __restrict__ out, long long Obs, int ldo) {
  __shared__ __align__(16) bf16 At[64][200];
  __shared__ __align__(16) bf16 Bs[64][200];
  int b = blockIdx.z;
  int tid = threadIdx.x;
  const bf16* Ab = A + (size_t)b * Abs + (size_t)blockIdx.x * 64 * DIM;
  const bf16* Bb = Bt + (size_t)b * Bbs + (size_t)blockIdx.y * 64 * DIM;
  int row = tid >> 2, cb = (tid & 3) * 48;
  int wave = tid >> 6, lane = tid & 63;
  int r = lane & 15, kq = lane >> 4;
  fx4 zero = {0.f, 0.f, 0.f, 0.f};
  fx4 acc[4];
  #pragma unroll
  for (int i = 0; i < 4; ++i) acc[i] = zero;
  #pragma unroll
  for (int kb = 0; kb < DIM; kb += 192) {
    if (kb) __syncthreads();   // all waves done reading previous K-step tiles
    {
      const i4* ga = (const i4*)(Ab + (size_t)row * DIM + kb + cb);
      const i4* gb = (const i4*)(Bb + (size_t)row * DIM + kb + cb);
      i4* la = (i4*)(&At[row][cb]);
      i4* lb = (i4*)(&Bs[row][cb]);
      #pragma unroll
      for (int p = 0; p < 6; ++p) { la[p] = ga[p]; lb[p] = gb[p]; }
    }
    __syncthreads();
    #pragma unroll
    for (int ks = 0; ks < 6; ++ks) {
      short8 af = *(const short8*)(&At[wave * 16 + r][ks * 32 + kq * 8]);
      #pragma unroll
      for (int ct = 0; ct < 4; ++ct) {
        short8 bfr = *(const short8*)(&Bs[ct * 16 + r][ks * 32 + kq * 8]);
        acc[ct] = MFMA(af, bfr, acc[ct]);
      }
    }
  }
  bf16* ob = out + (size_t)b * Obs
           + (size_t)(blockIdx.x * 64 + wave * 16 + kq * 4) * ldo + blockIdx.y * 64;
  #pragma unroll
  for (int ct = 0; ct < 4; ++ct)
    #pragma unroll
    for (int rr = 0; rr < 4; ++rr)
      ob[(size_t)rr * ldo + ct * 16 + r] = __float2bfloat16(acc[ct][rr]);
}

// -------- fused attention: S = Q*K^T (no-max softmax), O = P*V / rowsum --------
// EXACT round-0 kernel (measured 242 us kattn / 306 us total): grid (8, 49),
// 4 waves, m-tile 64, K staged in LDS (reg-staged), V direct global gathers,
// 2 barriers per m-iter. Six restructuring attempts (occupancy, read-halving,
// DMA staging, V prefetch schedules) all regressed -- every one tripped the
// 128-arch-VGPR boundary or added serialization. Do not modify phase liveness.
__global__ __launch_bounds__(256, 2) void kattn(const bf16* __restrict__ Qb,
                                                const bf16* __restrict__ Kb,
                                                const bf16* __restrict__ Vt,
                                                float* __restrict__ out) {
  __shared__ __align__(16) bf16 Kl[64][DIM + 8];   // 50176 B
  __shared__ __align__(16) bf16 Pl[4][16][68];     //  8704 B (stride 34 dw, odd/2)
  __shared__ float rsum[64];

  int b = blockIdx.x;
  int n0 = blockIdx.y * 64;
  int tid = threadIdx.x;
  int wave = tid >> 6, lane = tid & 63;
  int r = lane & 15, kq = lane >> 4;

  // Q fragments for this wave's 16 rows, full K=384 (12 k-steps)
  short8 qf[12];
  {
    const bf16* qp = Qb + ((size_t)b * SEQ + n0 + wave * 16 + r) * DIM + kq * 8;
    #pragma unroll
    for (int ks = 0; ks < 12; ++ks) qf[ks] = *(const short8*)(qp + ks * 32);
  }
  fx4 zero = {0.f, 0.f, 0.f, 0.f};
  fx4 acc[4][6];
  #pragma unroll
  for (int i = 0; i < 4; ++i)
    #pragma unroll
    for (int j = 0; j < 6; ++j) acc[i][j] = zero;
  float rs[4] = {0.f, 0.f, 0.f, 0.f};
  const float cexp = 0.07362223f;   // log2(e)/sqrt(384): exp(s*scale) = exp2(s*cexp)

  const bf16* kbase = Kb + (size_t)b * SEQ * DIM;
  const bf16* vbase = Vt + (size_t)b * DIM * SEQ;

  // staging geometry (per thread): one K row quarter
  int srow = tid >> 2, scb = (tid & 3) * 96;

  for (int im = 0; im < SEQ / 64; ++im) {
    int m0 = im * 64;
    { // stage K tile: 64 rows x 384 bf16 (reg-staged)
      const i4* g = (const i4*)(kbase + (size_t)(m0 + srow) * DIM + scb);
      i4* l = (i4*)(&Kl[srow][scb]);
      #pragma unroll
      for (int p = 0; p < 12; ++p) l[p] = g[p];
    }
    // V fragments direct from global (L2): latency hides under QK
    short8 vf[2][6];
    #pragma unroll
    for (int ks2 = 0; ks2 < 2; ++ks2)
      #pragma unroll
      for (int dtl = 0; dtl < 6; ++dtl) {
        int d = (wave * 6 + dtl) * 16 + r;
        vf[ks2][dtl] = *(const short8*)(vbase + (size_t)d * SEQ + m0 + ks2 * 32 + kq * 8);
      }
    __syncthreads();   // A: Kl ready; also all waves done PV(im-1) -> Pl free
    // S = Q * K^T : wave's 16 rows x 64 cols
    fx4 sa[4];
    #pragma unroll
    for (int ct = 0; ct < 4; ++ct) sa[ct] = zero;
    #pragma unroll
    for (int ks = 0; ks < 12; ++ks) {
      #pragma unroll
      for (int ct = 0; ct < 4; ++ct) {
        short8 bfr = *(const short8*)(&Kl[ct * 16 + r][ks * 32 + kq * 8]);
        sa[ct] = MFMA(qf[ks], bfr, sa[ct]);
      }
    }
    // exp (no max subtraction), partial rowsum (per-lane, reduce deferred), P -> LDS
    #pragma unroll
    for (int rr = 0; rr < 4; ++rr) {
      float e0 = exp2f(sa[0][rr] * cexp);
      float e1 = exp2f(sa[1][rr] * cexp);
      float e2 = exp2f(sa[2][rr] * cexp);
      float e3 = exp2f(sa[3][rr] * cexp);
      int row = kq * 4 + rr;
      Pl[wave][row][r]      = __float2bfloat16(e0);
      Pl[wave][row][16 + r] = __float2bfloat16(e1);
      Pl[wave][row][32 + r] = __float2bfloat16(e2);
      Pl[wave][row][48 + r] = __float2bfloat16(e3);
      rs[rr] += (e0 + e1) + (e2 + e3);
    }
    __syncthreads();   // B: Pl ready; also all waves done QK -> Kl free next iter
    // PV: O[rg*16+i][d] += P[rg*16+i][m] * V[m][d], wave's 96 d-cols
    #pragma unroll
    for (int ks2 = 0; ks2 < 2; ++ks2) {
      short8 pa[4];
      #pragma unroll
      for (int rg = 0; rg < 4; ++rg)
        pa[rg] = *(const short8*)(&Pl[rg][r][ks2 * 32 + kq * 8]);
      #pragma unroll
      for (int dtl = 0; dtl < 6; ++dtl) {
        #pragma unroll
        for (int rg = 0; rg < 4; ++rg)
          acc[rg][dtl] = MFMA(pa[rg], vf[ks2][dtl], acc[rg][dtl]);
      }
    }
  }
  // final rowsum reduce over the 16 r-lanes (cols partition), share across waves
  #pragma unroll
  for (int rr = 0; rr < 4; ++rr) {
    float v = rs[rr];
    v += __shfl_xor(v, 1);
    v += __shfl_xor(v, 2);
    v += __shfl_xor(v, 4);
    v += __shfl_xor(v, 8);
    if (r == 0) rsum[wave * 16 + kq * 4 + rr] = v;
  }
  __syncthreads();
  // epilogue: divide and store transposed: out[b][d][n]
  float* ob = out + (size_t)b * DIM * SEQ;
  #pragma unroll
  for (int rg = 0; rg < 4; ++rg) {
    #pragma unroll
    for (int rr = 0; rr < 4; ++rr) {
      float inv = 1.0f / rsum[rg * 16 + kq * 4 + rr];
      int n = n0 + rg * 16 + kq * 4 + rr;
      #pragma unroll
      for (int dtl = 0; dtl < 6; ++dtl) {
        int d = (wave * 6 + dtl) * 16 + r;
        ob[(size_t)d * SEQ + n] = acc[rg][dtl][rr] * inv;
      }
    }
  }
}

extern "C" void kernel_launch(void* const* d_in, const int* in_sizes, int n_in,
                              void* d_out, int out_size, void* d_ws, size_t ws_size,
                              hipStream_t stream) {
  const float* x  = (const float*)d_in[0];
  const float* w1 = (const float*)d_in[1];
  const float* w2 = (const float*)d_in[2];
  float* out = (float*)d_out;

  char* ws = (char*)d_ws;
  size_t SZ = (size_t)NBATCH * SEQ * DIM * sizeof(bf16);   // 19,267,584 B
  bf16* Kb  = (bf16*)(ws);                 // [B][N][C]
  bf16* Qb  = (bf16*)(ws + SZ);            // [B][N][C]
  bf16* Vt  = (bf16*)(ws + 2 * SZ);        // [B][C][N]
  bf16* w1b = (bf16*)(ws + 3 * SZ);
  bf16* w2b = (bf16*)(ws + 3 * SZ + (size_t)DIM * DIM * sizeof(bf16));

  // 1) transpose+convert x -> Kb
  ktrans<<<dim3(SEQ / 64, DIM / 64, NBATCH), 256, 0, stream>>>(x, Kb);
  // 2) weights -> bf16
  kwconv<<<dim3(DIM * DIM / 256), 256, 0, stream>>>(w1, w2, w1b, w2b);
  // 3) Q[b][n][d] = sum_c Kb[b][n][c] * w1[d][c]
  kgemm<<<dim3(SEQ / 64, DIM / 64, NBATCH), 256, 0, stream>>>(
      Kb, (long long)SEQ * DIM, w1b, 0LL, Qb, (long long)SEQ * DIM, DIM);
  // 4) Vt[b][d][m] = sum_c w2[d][c] * Kb[b][m][c]
  kgemm<<<dim3(DIM / 64, SEQ / 64, NBATCH), 256, 0, stream>>>(
      w2b, 0LL, Kb, (long long)SEQ * DIM, Vt, (long long)DIM * SEQ, SEQ);
  // 5) fused attention -> out[b][d][n]  (batch on blockIdx.x -> one XCD per batch)
  kattn<<<dim3(NBATCH, SEQ / 64), 256, 0, stream>>>(Qb, Kb, Vt, out);
}